// Round 1
// baseline (173.142 us; speedup 1.0000x reference)
//
#include <hip/hip_runtime.h>
#include <hip/hip_bf16.h>
#include <stdint.h>

#define T_SEQ 4096
#define CDIM  1024
#define NH    16
#define DHEAD 64
#define BAND  128

typedef __bf16 bf16;
typedef __attribute__((ext_vector_type(8))) __bf16 bf16x8;
typedef __attribute__((ext_vector_type(4))) float  f32x4;

// async global->LDS, 16B per lane; LDS dest = wave-uniform base + lane*16
__device__ __forceinline__ void async_ld16(const bf16* g, bf16* l) {
    __builtin_amdgcn_global_load_lds(
        (__attribute__((address_space(1))) void*)g,
        (__attribute__((address_space(3))) void*)l, 16, 0, 0);
}

// ---------------------------------------------------------------------------
// fp32 -> bf16 conversion of x, [Wq;Wk;Wv] (3072x1024), Wo
// ---------------------------------------------------------------------------
__global__ void cvt_all(const float* __restrict__ x,  const float* __restrict__ wq,
                        const float* __restrict__ wk, const float* __restrict__ wv,
                        const float* __restrict__ wo,
                        bf16* __restrict__ xb, bf16* __restrict__ wqkvb,
                        bf16* __restrict__ wob) {
    size_t i = (size_t)blockIdx.x * 256 + threadIdx.x;
    if (i < 4194304) { xb[i] = (bf16)x[i]; return; }
    size_t i2 = i - 4194304;
    if (i2 < 3145728) {
        int which = (int)(i2 >> 20);
        size_t off = i2 & 1048575;
        const float* src = (which == 0) ? wq : (which == 1 ? wk : wv);
        wqkvb[i2] = (bf16)src[off];
        return;
    }
    size_t i3 = i2 - 3145728;
    wob[i3] = (bf16)wo[i3];
}

// ---------------------------------------------------------------------------
// QKV GEMM: C[m,n] = sum_k A[m,k]*B[n,k]   A=4096x1024 (x), B=3072x1024 (Wqkv)
// 128x128 tile, BK=32, 4 waves (2x2 of 64x64), 16x16x32 bf16 MFMA.
// Epilogue scatters Q,K as (H,T,64) and V transposed as (H,64,T).
// ---------------------------------------------------------------------------
__global__ __launch_bounds__(256) void gemm_qkv(
        const bf16* __restrict__ A, const bf16* __restrict__ B,
        bf16* __restrict__ qb, bf16* __restrict__ kb, bf16* __restrict__ vtb) {
    const int K = 1024;
    __shared__ __align__(16) bf16 lds_a[128 * 32];
    __shared__ __align__(16) bf16 lds_b[128 * 32];
    int t = threadIdx.x;
    int w = t >> 6, l = t & 63;
    int quad = l >> 4, col = l & 15;
    int bx = blockIdx.x;
    int bm = bx & 31, bn = bx >> 5;          // 32 x 24 blocks
    int m0 = bm * 128, n0 = bn * 128;
    int wm = (w >> 1) * 64, wn = (w & 1) * 64;

    f32x4 acc[4][4];
#pragma unroll
    for (int i = 0; i < 4; i++)
#pragma unroll
        for (int j = 0; j < 4; j++) acc[i][j] = (f32x4){0.f, 0.f, 0.f, 0.f};

    int c0 = t, c1 = 256 + t;                 // two 16B chunks per thread
    int ra0 = c0 >> 2, ka0 = (c0 & 3) * 8;
    int ra1 = c1 >> 2, ka1 = (c1 & 3) * 8;
    bf16* la0 = lds_a + (size_t)(w * 64) * 8;
    bf16* la1 = lds_a + (size_t)(256 + w * 64) * 8;
    bf16* lb0 = lds_b + (size_t)(w * 64) * 8;
    bf16* lb1 = lds_b + (size_t)(256 + w * 64) * 8;

    for (int k0 = 0; k0 < K; k0 += 32) {
        async_ld16(A + (size_t)(m0 + ra0) * K + k0 + ka0, la0);
        async_ld16(A + (size_t)(m0 + ra1) * K + k0 + ka1, la1);
        async_ld16(B + (size_t)(n0 + ra0) * K + k0 + ka0, lb0);
        async_ld16(B + (size_t)(n0 + ra1) * K + k0 + ka1, lb1);
        __syncthreads();
        const bf16x8* pa = (const bf16x8*)lds_a;
        const bf16x8* pb = (const bf16x8*)lds_b;
        bf16x8 af[4], bfr[4];
#pragma unroll
        for (int i = 0; i < 4; i++) af[i]  = pa[(wm + i * 16 + col) * 4 + quad];
#pragma unroll
        for (int j = 0; j < 4; j++) bfr[j] = pb[(wn + j * 16 + col) * 4 + quad];
#pragma unroll
        for (int i = 0; i < 4; i++)
#pragma unroll
            for (int j = 0; j < 4; j++)
                acc[i][j] = __builtin_amdgcn_mfma_f32_16x16x32_bf16(af[i], bfr[j], acc[i][j], 0, 0, 0);
        __syncthreads();
    }
    // epilogue: C/D layout col = lane&15, row = quad*4 + r
#pragma unroll
    for (int i = 0; i < 4; i++)
#pragma unroll
        for (int j = 0; j < 4; j++) {
            int mbase = m0 + wm + i * 16 + quad * 4;
            int ncol = n0 + wn + j * 16 + col;
            int which = ncol >> 10;
            int o = ncol & 1023;
            int h = o >> 6, d = o & 63;
#pragma unroll
            for (int r = 0; r < 4; r++) {
                int tt = mbase + r;
                bf16 v = (bf16)acc[i][j][r];
                if (which == 0)       qb[((size_t)(h * T_SEQ + tt)) * 64 + d] = v;
                else if (which == 1)  kb[((size_t)(h * T_SEQ + tt)) * 64 + d] = v;
                else                  vtb[((size_t)(h * 64 + d)) * T_SEQ + tt] = v;
            }
        }
}

// ---------------------------------------------------------------------------
// Banded flash attention: block = (head h, q-tile of 128 rows), 4 waves,
// wave w owns 32 q-rows. Two K-tiles: [i0-128,i0) and diagonal [i0,i0+128).
// ---------------------------------------------------------------------------
__global__ __launch_bounds__(256) void attn(
        const bf16* __restrict__ qbuf, const bf16* __restrict__ kbuf,
        const bf16* __restrict__ vtbuf, bf16* __restrict__ yb) {
    __shared__ __align__(16) bf16 p_lds[4 * 32 * 128];   // per-wave P regions
    int t = threadIdx.x;
    int w = t >> 6, l = t & 63;
    int quad = l >> 4, col = l & 15;
    int bx = blockIdx.x;
    int h = bx >> 5;          // 16 heads
    int qt = bx & 31;         // 32 q tiles
    int i0 = qt * 128;
    int rowbase = i0 + w * 32;

    const bf16* Q  = qbuf  + (size_t)h * T_SEQ * 64;
    const bf16* Kp = kbuf  + (size_t)h * T_SEQ * 64;
    const bf16* Vt = vtbuf + (size_t)h * 64 * T_SEQ;

    f32x4 o_acc[2][4];
#pragma unroll
    for (int mi = 0; mi < 2; mi++)
#pragma unroll
        for (int di = 0; di < 4; di++) o_acc[mi][di] = (f32x4){0.f, 0.f, 0.f, 0.f};
    float m_run[2][4], l_run[2][4];
#pragma unroll
    for (int mi = 0; mi < 2; mi++)
#pragma unroll
        for (int r = 0; r < 4; r++) { m_run[mi][r] = -3.0e38f; l_run[mi][r] = 0.f; }

    // Q fragments: A-layout  Q[m=lane&15][k=quad*8+j]
    bf16x8 qf[2][2];
#pragma unroll
    for (int mi = 0; mi < 2; mi++)
#pragma unroll
        for (int kk = 0; kk < 2; kk++)
            qf[mi][kk] = *(const bf16x8*)(Q + (size_t)(rowbase + mi * 16 + col) * 64 + kk * 32 + quad * 8);

    bf16* myp = p_lds + (size_t)w * (32 * 128);

    int ktstart = (qt == 0) ? 1 : 0;
    for (int kt = ktstart; kt < 2; kt++) {
        int j0 = i0 + (kt - 1) * 128;
        f32x4 s[2][8];
#pragma unroll
        for (int mi = 0; mi < 2; mi++)
#pragma unroll
            for (int nj = 0; nj < 8; nj++) s[mi][nj] = (f32x4){0.f, 0.f, 0.f, 0.f};
        // S = Q K^T
#pragma unroll
        for (int nj = 0; nj < 8; nj++)
#pragma unroll
            for (int kk = 0; kk < 2; kk++) {
                bf16x8 kf = *(const bf16x8*)(Kp + (size_t)(j0 + nj * 16 + col) * 64 + kk * 32 + quad * 8);
#pragma unroll
                for (int mi = 0; mi < 2; mi++)
                    s[mi][nj] = __builtin_amdgcn_mfma_f32_16x16x32_bf16(qf[mi][kk], kf, s[mi][nj], 0, 0, 0);
            }
        // mask + scale (1/sqrt(64) = 0.125)
#pragma unroll
        for (int mi = 0; mi < 2; mi++)
#pragma unroll
            for (int nj = 0; nj < 8; nj++)
#pragma unroll
                for (int r = 0; r < 4; r++) {
                    int ii = rowbase + mi * 16 + quad * 4 + r;
                    int jj = j0 + nj * 16 + col;
                    bool ok = (kt == 1) ? (jj <= ii) : (ii - jj < BAND);
                    s[mi][nj][r] = ok ? s[mi][nj][r] * 0.125f : -3.0e38f;
                }
        // online softmax update (rows split across 16-lane groups)
#pragma unroll
        for (int mi = 0; mi < 2; mi++)
#pragma unroll
            for (int r = 0; r < 4; r++) {
                float mx = -3.0e38f;
#pragma unroll
                for (int nj = 0; nj < 8; nj++) mx = fmaxf(mx, s[mi][nj][r]);
                mx = fmaxf(mx, __shfl_xor(mx, 1));
                mx = fmaxf(mx, __shfl_xor(mx, 2));
                mx = fmaxf(mx, __shfl_xor(mx, 4));
                mx = fmaxf(mx, __shfl_xor(mx, 8));
                float mnew = fmaxf(m_run[mi][r], mx);
                float alpha = __expf(m_run[mi][r] - mnew);
                m_run[mi][r] = mnew;
                float rs = 0.f;
#pragma unroll
                for (int nj = 0; nj < 8; nj++) {
                    float p = __expf(s[mi][nj][r] - mnew);
                    s[mi][nj][r] = p;
                    rs += p;
                }
                rs += __shfl_xor(rs, 1);
                rs += __shfl_xor(rs, 2);
                rs += __shfl_xor(rs, 4);
                rs += __shfl_xor(rs, 8);
                l_run[mi][r] = l_run[mi][r] * alpha + rs;
#pragma unroll
                for (int di = 0; di < 4; di++) o_acc[mi][di][r] *= alpha;
            }
        // P: C/D layout -> LDS (per-wave region, no cross-wave barrier needed)
#pragma unroll
        for (int mi = 0; mi < 2; mi++)
#pragma unroll
            for (int nj = 0; nj < 8; nj++)
#pragma unroll
                for (int r = 0; r < 4; r++) {
                    int row = mi * 16 + quad * 4 + r;
                    int c = nj * 16 + col;
                    myp[row * 128 + c] = (bf16)s[mi][nj][r];
                }
        // O += P V   (A-frags of P from LDS, B-frags of V from Vt, t-contiguous)
#pragma unroll
        for (int kj = 0; kj < 4; kj++) {
            bf16x8 pf[2];
#pragma unroll
            for (int mi = 0; mi < 2; mi++)
                pf[mi] = *(const bf16x8*)(myp + (mi * 16 + col) * 128 + kj * 32 + quad * 8);
#pragma unroll
            for (int di = 0; di < 4; di++) {
                bf16x8 vf = *(const bf16x8*)(Vt + (size_t)(di * 16 + col) * T_SEQ + j0 + kj * 32 + quad * 8);
#pragma unroll
                for (int mi = 0; mi < 2; mi++)
                    o_acc[mi][di] = __builtin_amdgcn_mfma_f32_16x16x32_bf16(pf[mi], vf, o_acc[mi][di], 0, 0, 0);
            }
        }
    }
    // y[t, h*64+d] = O / l
#pragma unroll
    for (int mi = 0; mi < 2; mi++)
#pragma unroll
        for (int di = 0; di < 4; di++)
#pragma unroll
            for (int r = 0; r < 4; r++) {
                int tt = rowbase + mi * 16 + quad * 4 + r;
                int c = h * 64 + di * 16 + col;
                yb[(size_t)tt * CDIM + c] = (bf16)(o_acc[mi][di][r] / l_run[mi][r]);
            }
}

// ---------------------------------------------------------------------------
// Output projection: out[t,o] = sum_c y[t,c]*Wo[o,c], fp32 out
// ---------------------------------------------------------------------------
__global__ __launch_bounds__(256) void gemm_proj(
        const bf16* __restrict__ A, const bf16* __restrict__ B,
        float* __restrict__ Cout) {
    const int K = 1024;
    __shared__ __align__(16) bf16 lds_a[128 * 32];
    __shared__ __align__(16) bf16 lds_b[128 * 32];
    int t = threadIdx.x;
    int w = t >> 6, l = t & 63;
    int quad = l >> 4, col = l & 15;
    int bx = blockIdx.x;
    int bm = bx & 31, bn = bx >> 5;          // 32 x 8 blocks
    int m0 = bm * 128, n0 = bn * 128;
    int wm = (w >> 1) * 64, wn = (w & 1) * 64;

    f32x4 acc[4][4];
#pragma unroll
    for (int i = 0; i < 4; i++)
#pragma unroll
        for (int j = 0; j < 4; j++) acc[i][j] = (f32x4){0.f, 0.f, 0.f, 0.f};

    int c0 = t, c1 = 256 + t;
    int ra0 = c0 >> 2, ka0 = (c0 & 3) * 8;
    int ra1 = c1 >> 2, ka1 = (c1 & 3) * 8;
    bf16* la0 = lds_a + (size_t)(w * 64) * 8;
    bf16* la1 = lds_a + (size_t)(256 + w * 64) * 8;
    bf16* lb0 = lds_b + (size_t)(w * 64) * 8;
    bf16* lb1 = lds_b + (size_t)(256 + w * 64) * 8;

    for (int k0 = 0; k0 < K; k0 += 32) {
        async_ld16(A + (size_t)(m0 + ra0) * K + k0 + ka0, la0);
        async_ld16(A + (size_t)(m0 + ra1) * K + k0 + ka1, la1);
        async_ld16(B + (size_t)(n0 + ra0) * K + k0 + ka0, lb0);
        async_ld16(B + (size_t)(n0 + ra1) * K + k0 + ka1, lb1);
        __syncthreads();
        const bf16x8* pa = (const bf16x8*)lds_a;
        const bf16x8* pb = (const bf16x8*)lds_b;
        bf16x8 af[4], bfr[4];
#pragma unroll
        for (int i = 0; i < 4; i++) af[i]  = pa[(wm + i * 16 + col) * 4 + quad];
#pragma unroll
        for (int j = 0; j < 4; j++) bfr[j] = pb[(wn + j * 16 + col) * 4 + quad];
#pragma unroll
        for (int i = 0; i < 4; i++)
#pragma unroll
            for (int j = 0; j < 4; j++)
                acc[i][j] = __builtin_amdgcn_mfma_f32_16x16x32_bf16(af[i], bfr[j], acc[i][j], 0, 0, 0);
        __syncthreads();
    }
#pragma unroll
    for (int i = 0; i < 4; i++)
#pragma unroll
        for (int j = 0; j < 4; j++) {
            int mbase = m0 + wm + i * 16 + quad * 4;
            int ncol = n0 + wn + j * 16 + col;
#pragma unroll
            for (int r = 0; r < 4; r++)
                Cout[(size_t)(mbase + r) * CDIM + ncol] = acc[i][j][r];
        }
}

extern "C" void kernel_launch(void* const* d_in, const int* in_sizes, int n_in,
                              void* d_out, int out_size, void* d_ws, size_t ws_size,
                              hipStream_t stream) {
    const float* x  = (const float*)d_in[0];
    const float* Wq = (const float*)d_in[1];
    const float* Wk = (const float*)d_in[2];
    const float* Wv = (const float*)d_in[3];
    const float* Wo = (const float*)d_in[4];
    float* out = (float*)d_out;

    char* ws = (char*)d_ws;
    bf16* xb    = (bf16*)(ws);                        //  8 MB  x bf16
    bf16* wqkvb = (bf16*)(ws + ((size_t)8  << 20));   //  6 MB  [Wq;Wk;Wv]
    bf16* wob   = (bf16*)(ws + ((size_t)14 << 20));   //  2 MB  Wo
    bf16* qb    = (bf16*)(ws + ((size_t)16 << 20));   //  8 MB  Q (H,T,64)
    bf16* kb    = (bf16*)(ws + ((size_t)24 << 20));   //  8 MB  K (H,T,64)
    bf16* vtb   = (bf16*)(ws + ((size_t)32 << 20));   //  8 MB  V^T (H,64,T)
    bf16* yb    = (bf16*)(ws + ((size_t)40 << 20));   //  8 MB  y (T,C)

    cvt_all<<<32768, 256, 0, stream>>>(x, Wq, Wk, Wv, Wo, xb, wqkvb, wob);
    gemm_qkv<<<768, 256, 0, stream>>>(xb, wqkvb, qb, kb, vtb);
    attn<<<512, 256, 0, stream>>>(qb, kb, vtb, yb);
    gemm_proj<<<256, 256, 0, stream>>>(yb, wob, out);
}

// Round 2
// 155.874 us; speedup vs baseline: 1.1108x; 1.1108x over previous
//
#include <hip/hip_runtime.h>
#include <hip/hip_bf16.h>
#include <stdint.h>

#define T_SEQ 4096
#define CDIM  1024
#define NH    16
#define DHEAD 64
#define BAND  128

typedef __bf16 bf16;
typedef __attribute__((ext_vector_type(8))) __bf16 bf16x8;
typedef __attribute__((ext_vector_type(4))) float  f32x4;

__device__ __forceinline__ void async_ld16(const bf16* g, bf16* l) {
    __builtin_amdgcn_global_load_lds(
        (__attribute__((address_space(1))) void*)g,
        (__attribute__((address_space(3))) void*)l, 16, 0, 0);
}

// ---------------------------------------------------------------------------
// fp32 -> bf16, 8 elems/thread (2x float4 load, 1x 16B store)
// layout: x (4194304), [Wq;Wk;Wv] (3145728), Wo (1048576); groups of 8
// ---------------------------------------------------------------------------
__global__ void cvt_all(const float* __restrict__ x,  const float* __restrict__ wq,
                        const float* __restrict__ wk, const float* __restrict__ wv,
                        const float* __restrict__ wo,
                        bf16* __restrict__ xb, bf16* __restrict__ wqkvb,
                        bf16* __restrict__ wob) {
    size_t g = (size_t)blockIdx.x * 256 + threadIdx.x;   // group of 8 elems
    const float* s; bf16* d;
    if (g < 524288) {                       // x
        s = x + g * 8; d = xb + g * 8;
    } else if (g < 917504) {                // Wq/Wk/Wv -> wqkvb
        size_t i2 = (g - 524288) * 8;
        int which = (int)(i2 >> 20);
        s = ((which == 0) ? wq : (which == 1) ? wk : wv) + (i2 & 1048575);
        d = wqkvb + i2;
    } else {                                // Wo
        size_t i3 = (g - 917504) * 8;
        s = wo + i3; d = wob + i3;
    }
    const float4* sv = (const float4*)s;
    float4 a = sv[0], b = sv[1];
    bf16x8 o;
    o[0] = (bf16)a.x; o[1] = (bf16)a.y; o[2] = (bf16)a.z; o[3] = (bf16)a.w;
    o[4] = (bf16)b.x; o[5] = (bf16)b.y; o[6] = (bf16)b.z; o[7] = (bf16)b.w;
    *(bf16x8*)d = o;
}

// ---------------------------------------------------------------------------
// QKV GEMM: C[m,n] = sum_k A[m,k]*B[n,k]   A=4096x1024 (x), B=3072x1024 (Wqkv)
// 128x128 tile, BK=32, 4 waves (2x2 of 64x64), 16x16x32 bf16 MFMA.
// Epilogue scatters Q,K as (H,T,64) and V transposed as (H,64,T).
// ---------------------------------------------------------------------------
__global__ __launch_bounds__(256) void gemm_qkv(
        const bf16* __restrict__ A, const bf16* __restrict__ B,
        bf16* __restrict__ qb, bf16* __restrict__ kb, bf16* __restrict__ vtb) {
    const int K = 1024;
    __shared__ __align__(16) bf16 lds_a[128 * 32];
    __shared__ __align__(16) bf16 lds_b[128 * 32];
    int t = threadIdx.x;
    int w = t >> 6, l = t & 63;
    int quad = l >> 4, col = l & 15;
    int bx = blockIdx.x;
    int bm = bx & 31, bn = bx >> 5;          // 32 x 24 blocks
    int m0 = bm * 128, n0 = bn * 128;
    int wm = (w >> 1) * 64, wn = (w & 1) * 64;

    f32x4 acc[4][4];
#pragma unroll
    for (int i = 0; i < 4; i++)
#pragma unroll
        for (int j = 0; j < 4; j++) acc[i][j] = (f32x4){0.f, 0.f, 0.f, 0.f};

    int c0 = t, c1 = 256 + t;
    int ra0 = c0 >> 2, ka0 = (c0 & 3) * 8;
    int ra1 = c1 >> 2, ka1 = (c1 & 3) * 8;
    bf16* la0 = lds_a + (size_t)(w * 64) * 8;
    bf16* la1 = lds_a + (size_t)(256 + w * 64) * 8;
    bf16* lb0 = lds_b + (size_t)(w * 64) * 8;
    bf16* lb1 = lds_b + (size_t)(256 + w * 64) * 8;

    for (int k0 = 0; k0 < K; k0 += 32) {
        async_ld16(A + (size_t)(m0 + ra0) * K + k0 + ka0, la0);
        async_ld16(A + (size_t)(m0 + ra1) * K + k0 + ka1, la1);
        async_ld16(B + (size_t)(n0 + ra0) * K + k0 + ka0, lb0);
        async_ld16(B + (size_t)(n0 + ra1) * K + k0 + ka1, lb1);
        __syncthreads();
        const bf16x8* pa = (const bf16x8*)lds_a;
        const bf16x8* pb = (const bf16x8*)lds_b;
        bf16x8 af[4], bfr[4];
#pragma unroll
        for (int i = 0; i < 4; i++) af[i]  = pa[(wm + i * 16 + col) * 4 + quad];
#pragma unroll
        for (int j = 0; j < 4; j++) bfr[j] = pb[(wn + j * 16 + col) * 4 + quad];
#pragma unroll
        for (int i = 0; i < 4; i++)
#pragma unroll
            for (int j = 0; j < 4; j++)
                acc[i][j] = __builtin_amdgcn_mfma_f32_16x16x32_bf16(af[i], bfr[j], acc[i][j], 0, 0, 0);
        __syncthreads();
    }
#pragma unroll
    for (int i = 0; i < 4; i++)
#pragma unroll
        for (int j = 0; j < 4; j++) {
            int mbase = m0 + wm + i * 16 + quad * 4;
            int ncol = n0 + wn + j * 16 + col;
            int which = ncol >> 10;
            int o = ncol & 1023;
            int h = o >> 6, d = o & 63;
#pragma unroll
            for (int r = 0; r < 4; r++) {
                int tt = mbase + r;
                bf16 v = (bf16)acc[i][j][r];
                if (which == 0)       qb[((size_t)(h * T_SEQ + tt)) * 64 + d] = v;
                else if (which == 1)  kb[((size_t)(h * T_SEQ + tt)) * 64 + d] = v;
                else                  vtb[((size_t)(h * 64 + d)) * T_SEQ + tt] = v;
            }
        }
}

// ---------------------------------------------------------------------------
// Banded attention, single-pass: block = (head, 128 q-rows), wave owns 32 rows.
// Wave window = keys [rowbase-128, rowbase+32) = 10 tiles of 16 (exactly the
// band support). One softmax pass, no online rescale.
// ---------------------------------------------------------------------------
#define PSTR 168   // padded LDS stride for P (elems): 84 dwords -> banks spread

__global__ __launch_bounds__(256) void attn(
        const bf16* __restrict__ qbuf, const bf16* __restrict__ kbuf,
        const bf16* __restrict__ vtbuf, bf16* __restrict__ yb) {
    __shared__ __align__(16) bf16 p_lds[4 * 32 * PSTR];
    int t = threadIdx.x;
    int w = t >> 6, l = t & 63;
    int quad = l >> 4, col = l & 15;
    int h = blockIdx.x >> 5;
    int qt = blockIdx.x & 31;
    int i0 = qt * 128;
    int rowbase = i0 + w * 32;
    int jbase = rowbase - 128;

    const bf16* Q  = qbuf  + (size_t)h * T_SEQ * 64;
    const bf16* Kp = kbuf  + (size_t)h * T_SEQ * 64;
    const bf16* Vt = vtbuf + (size_t)h * 64 * T_SEQ;

    // Q fragments (A-layout): Q[m=col][k=quad*8+e], two 16-row m-tiles, two k-chunks
    bf16x8 qf[2][2];
#pragma unroll
    for (int mi = 0; mi < 2; mi++)
#pragma unroll
        for (int kk = 0; kk < 2; kk++)
            qf[mi][kk] = *(const bf16x8*)(Q + (size_t)(rowbase + mi * 16 + col) * 64 + kk * 32 + quad * 8);

    // S = Q K^T over the 160-key window
    f32x4 s[2][10];
#pragma unroll
    for (int mi = 0; mi < 2; mi++)
#pragma unroll
        for (int nj = 0; nj < 10; nj++) s[mi][nj] = (f32x4){0.f, 0.f, 0.f, 0.f};
#pragma unroll
    for (int nj = 0; nj < 10; nj++) {
        int jr = jbase + nj * 16 + col;
        int jl = jr < 0 ? 0 : jr;           // clamp (masked later)
#pragma unroll
        for (int kk = 0; kk < 2; kk++) {
            bf16x8 kf = *(const bf16x8*)(Kp + (size_t)jl * 64 + kk * 32 + quad * 8);
#pragma unroll
            for (int mi = 0; mi < 2; mi++)
                s[mi][nj] = __builtin_amdgcn_mfma_f32_16x16x32_bf16(qf[mi][kk], kf, s[mi][nj], 0, 0, 0);
        }
    }

    // mask + scale + softmax (single pass; rows split across 16-lane groups)
    float l_run[2][4];
#pragma unroll
    for (int mi = 0; mi < 2; mi++)
#pragma unroll
        for (int r = 0; r < 4; r++) {
            int ii = rowbase + mi * 16 + quad * 4 + r;
            float mx = -3.0e38f;
#pragma unroll
            for (int nj = 0; nj < 10; nj++) {
                int jj = jbase + nj * 16 + col;
                bool ok = (jj >= 0) && ((unsigned)(ii - jj) < (unsigned)BAND);
                float v = ok ? s[mi][nj][r] * 0.125f : -3.0e38f;
                s[mi][nj][r] = v;
                mx = fmaxf(mx, v);
            }
            mx = fmaxf(mx, __shfl_xor(mx, 1));
            mx = fmaxf(mx, __shfl_xor(mx, 2));
            mx = fmaxf(mx, __shfl_xor(mx, 4));
            mx = fmaxf(mx, __shfl_xor(mx, 8));
            float rs = 0.f;
#pragma unroll
            for (int nj = 0; nj < 10; nj++) {
                float p = __expf(s[mi][nj][r] - mx);   // masked -> exp(-huge) = 0
                s[mi][nj][r] = p;
                rs += p;
            }
            rs += __shfl_xor(rs, 1);
            rs += __shfl_xor(rs, 2);
            rs += __shfl_xor(rs, 4);
            rs += __shfl_xor(rs, 8);
            l_run[mi][r] = rs;
        }

    // P -> per-wave LDS region (C/D layout scatter)
    bf16* myp = p_lds + (size_t)w * (32 * PSTR);
#pragma unroll
    for (int mi = 0; mi < 2; mi++)
#pragma unroll
        for (int nj = 0; nj < 10; nj++)
#pragma unroll
            for (int r = 0; r < 4; r++)
                myp[(mi * 16 + quad * 4 + r) * PSTR + nj * 16 + col] = (bf16)s[mi][nj][r];

    // O = P V over the 160-key window
    f32x4 o_acc[2][4];
#pragma unroll
    for (int mi = 0; mi < 2; mi++)
#pragma unroll
        for (int di = 0; di < 4; di++) o_acc[mi][di] = (f32x4){0.f, 0.f, 0.f, 0.f};
#pragma unroll
    for (int kj = 0; kj < 5; kj++) {
        int jv = jbase + kj * 32 + quad * 8;
        int jvc = jv < 0 ? 0 : jv;          // clamp; P is 0 there
        bf16x8 pf[2];
#pragma unroll
        for (int mi = 0; mi < 2; mi++)
            pf[mi] = *(const bf16x8*)(myp + (mi * 16 + col) * PSTR + kj * 32 + quad * 8);
#pragma unroll
        for (int di = 0; di < 4; di++) {
            bf16x8 vf = *(const bf16x8*)(Vt + (size_t)(di * 16 + col) * T_SEQ + jvc);
#pragma unroll
            for (int mi = 0; mi < 2; mi++)
                o_acc[mi][di] = __builtin_amdgcn_mfma_f32_16x16x32_bf16(pf[mi], vf, o_acc[mi][di], 0, 0, 0);
        }
    }

    // y[t, h*64+d] = O / l
#pragma unroll
    for (int mi = 0; mi < 2; mi++)
#pragma unroll
        for (int di = 0; di < 4; di++)
#pragma unroll
            for (int r = 0; r < 4; r++) {
                int tt = rowbase + mi * 16 + quad * 4 + r;
                int c = h * 64 + di * 16 + col;
                yb[(size_t)tt * CDIM + c] = (bf16)(o_acc[mi][di][r] / l_run[mi][r]);
            }
}

// ---------------------------------------------------------------------------
// Output projection: out[t,o] = sum_c y[t,c]*Wo[o,c], fp32 out.
// 64x128 tile -> 512 blocks (2 blocks/CU). 4 waves as 2x2 of 32x64.
// ---------------------------------------------------------------------------
__global__ __launch_bounds__(256) void gemm_proj(
        const bf16* __restrict__ A, const bf16* __restrict__ B,
        float* __restrict__ Cout) {
    const int K = 1024;
    __shared__ __align__(16) bf16 lds_a[64 * 32];
    __shared__ __align__(16) bf16 lds_b[128 * 32];
    int t = threadIdx.x;
    int w = t >> 6, l = t & 63;
    int quad = l >> 4, col = l & 15;
    int bx = blockIdx.x;
    int bm = bx & 63, bn = bx >> 6;          // 64 x 8 blocks
    int m0 = bm * 64, n0 = bn * 128;
    int wm = (w >> 1) * 32, wn = (w & 1) * 64;

    f32x4 acc[2][4];
#pragma unroll
    for (int i = 0; i < 2; i++)
#pragma unroll
        for (int j = 0; j < 4; j++) acc[i][j] = (f32x4){0.f, 0.f, 0.f, 0.f};

    int ra0 = t >> 2, ka0 = (t & 3) * 8;            // A: 1 chunk (256 chunks)
    int c1 = t, c2 = 256 + t;                        // B: 2 chunks (512 chunks)
    int rb1 = c1 >> 2, kb1 = (c1 & 3) * 8;
    int rb2 = c2 >> 2, kb2 = (c2 & 3) * 8;
    bf16* la0 = lds_a + (size_t)(w * 64) * 8;
    bf16* lb1 = lds_b + (size_t)(w * 64) * 8;
    bf16* lb2 = lds_b + (size_t)(256 + w * 64) * 8;

    for (int k0 = 0; k0 < K; k0 += 32) {
        async_ld16(A + (size_t)(m0 + ra0) * K + k0 + ka0, la0);
        async_ld16(B + (size_t)(n0 + rb1) * K + k0 + kb1, lb1);
        async_ld16(B + (size_t)(n0 + rb2) * K + k0 + kb2, lb2);
        __syncthreads();
        const bf16x8* pa = (const bf16x8*)lds_a;
        const bf16x8* pb = (const bf16x8*)lds_b;
        bf16x8 af[2], bfr[4];
#pragma unroll
        for (int i = 0; i < 2; i++) af[i]  = pa[(wm + i * 16 + col) * 4 + quad];
#pragma unroll
        for (int j = 0; j < 4; j++) bfr[j] = pb[(wn + j * 16 + col) * 4 + quad];
#pragma unroll
        for (int i = 0; i < 2; i++)
#pragma unroll
            for (int j = 0; j < 4; j++)
                acc[i][j] = __builtin_amdgcn_mfma_f32_16x16x32_bf16(af[i], bfr[j], acc[i][j], 0, 0, 0);
        __syncthreads();
    }
#pragma unroll
    for (int i = 0; i < 2; i++)
#pragma unroll
        for (int j = 0; j < 4; j++) {
            int mbase = m0 + wm + i * 16 + quad * 4;
            int ncol = n0 + wn + j * 16 + col;
#pragma unroll
            for (int r = 0; r < 4; r++)
                Cout[(size_t)(mbase + r) * CDIM + ncol] = acc[i][j][r];
        }
}

extern "C" void kernel_launch(void* const* d_in, const int* in_sizes, int n_in,
                              void* d_out, int out_size, void* d_ws, size_t ws_size,
                              hipStream_t stream) {
    const float* x  = (const float*)d_in[0];
    const float* Wq = (const float*)d_in[1];
    const float* Wk = (const float*)d_in[2];
    const float* Wv = (const float*)d_in[3];
    const float* Wo = (const float*)d_in[4];
    float* out = (float*)d_out;

    char* ws = (char*)d_ws;
    bf16* xb    = (bf16*)(ws);                        //  8 MB  x bf16
    bf16* wqkvb = (bf16*)(ws + ((size_t)8  << 20));   //  6 MB  [Wq;Wk;Wv]
    bf16* wob   = (bf16*)(ws + ((size_t)14 << 20));   //  2 MB  Wo
    bf16* qb    = (bf16*)(ws + ((size_t)16 << 20));   //  8 MB  Q (H,T,64)
    bf16* kb    = (bf16*)(ws + ((size_t)24 << 20));   //  8 MB  K (H,T,64)
    bf16* vtb   = (bf16*)(ws + ((size_t)32 << 20));   //  8 MB  V^T (H,64,T)
    bf16* yb    = (bf16*)(ws + ((size_t)40 << 20));   //  8 MB  y (T,C)

    cvt_all<<<4096, 256, 0, stream>>>(x, Wq, Wk, Wv, Wo, xb, wqkvb, wob);
    gemm_qkv<<<768, 256, 0, stream>>>(xb, wqkvb, qb, kb, vtb);
    attn<<<512, 256, 0, stream>>>(qb, kb, vtb, yb);
    gemm_proj<<<512, 256, 0, stream>>>(yb, wob, out);
}